// Round 12
// baseline (141.609 us; speedup 1.0000x reference)
//
#include <hip/hip_runtime.h>
#include <hip/hip_bf16.h>
#include <stdint.h>

// GCN 2-layer + linear head. bf16 node tables + MFMA gemm1; gemm2 FUSED into
// agg1 (LDS matvec vs fp32 W2). CSR build = fixed-capacity bucket sort
// (4096/bucket), register-staged single-pass scatter, dtype flag from prep.
// agg1 is at its compulsory per-XCD L2-fill floor (FETCH == 8*0.86*table).

#define THREADS 256
#define NBUCK_MAX 1024
#define CAP 4096
#define CAPB_LOG 12          // 4096 entries per bucket, fixed
#define SC_EPT 16            // edges per thread in scatter (4096/block)

typedef __attribute__((ext_vector_type(8))) short short8;
typedef __attribute__((ext_vector_type(4))) float f32x4;
union frag_u { uint4 u4; short8 s8; };

__device__ __forceinline__ unsigned int pack_bf2(float a, float b) {
    unsigned int ua = __float_as_uint(a);
    unsigned int ub = __float_as_uint(b);
    ua = (ua + 0x7FFFu + ((ua >> 16) & 1u)) >> 16;
    ub = (ub + 0x7FFFu + ((ub >> 16) & 1u)) >> 16;
    return ua | (ub << 16);
}
__device__ __forceinline__ unsigned short bf16r(float a) {
    unsigned int ua = __float_as_uint(a);
    return (unsigned short)((ua + 0x7FFFu + ((ua >> 16) & 1u)) >> 16);
}
__device__ __forceinline__ float bf_lo(unsigned int u) { return __uint_as_float(u << 16); }
__device__ __forceinline__ float bf_hi(unsigned int u) { return __uint_as_float(u & 0xFFFF0000u); }

__device__ __forceinline__ int detect64(const unsigned int* w) {
    int is64 = 1;
    #pragma unroll
    for (int i = 1; i < 64; i += 2) {
        if (w[i] != 0u) { is64 = 0; break; }
    }
    return is64;
}

// block 0: dtype flag + pack W1 into MFMA B-frag layout; blocks 1+: init cursors.
__global__ void k_prep(const unsigned int* ei_words, int* flag,
                       int* bucket_cursor, int B,
                       const float* __restrict__ W1, uint4* __restrict__ w1f) {
    int b = blockIdx.x;
    int t = threadIdx.x;
    if (b == 0) {
        if (t == 0) *flag = detect64(ei_words);
        // B-frag (16x16x32): lane l, elem e -> B[k][c], k = kt*32+(l>>4)*8+e, c = ct*16+(l&15).
        for (int i = t; i < 1024; i += THREADS) {
            int l = i & 63;
            int f = i >> 6;                 // ct*4 + kt
            int ct = f >> 2, kt = f & 3;
            int c = ct * 16 + (l & 15);
            int k0 = kt * 32 + (l >> 4) * 8;
            unsigned int r0 = pack_bf2(W1[(k0 + 0) * 64 + c], W1[(k0 + 1) * 64 + c]);
            unsigned int r1 = pack_bf2(W1[(k0 + 2) * 64 + c], W1[(k0 + 3) * 64 + c]);
            unsigned int r2 = pack_bf2(W1[(k0 + 4) * 64 + c], W1[(k0 + 5) * 64 + c]);
            unsigned int r3 = pack_bf2(W1[(k0 + 6) * 64 + c], W1[(k0 + 7) * 64 + c]);
            w1f[i] = make_uint4(r0, r1, r2, r3);
        }
    } else {
        int i = (b - 1) * THREADS + t;
        if (i < B) bucket_cursor[i] = i << CAPB_LOG;
    }
}

// Single-pass register-staged scatter: 16 edges/thread in registers (independent
// load burst), LDS hist, one reserve atomic per (block,bucket), scatter from regs.
__global__ void k_bucket_scatter(const void* ei, const int* __restrict__ flag,
                                 int* bucket_cursor, unsigned int* packed, int E, int B) {
    __shared__ int h[NBUCK_MAX];
    __shared__ int base[NBUCK_MAX];
    int t = threadIdx.x;
    for (int i = t; i < B; i += THREADS) h[i] = 0;
    bool is64 = (*flag != 0);
    __syncthreads();
    int lo = blockIdx.x * (THREADS * SC_EPT);
    const long long* p64 = (const long long*)ei;
    const int* p32 = (const int*)ei;

    int srcv[SC_EPT], dstv[SC_EPT];
    if (is64) {
        #pragma unroll
        for (int i = 0; i < SC_EPT; ++i) {
            int e = lo + i * THREADS + t;
            int ec = (e < E) ? e : (E - 1);
            srcv[i] = (int)p64[ec];
            dstv[i] = (e < E) ? (int)p64[(size_t)E + ec] : -1;
        }
    } else {
        #pragma unroll
        for (int i = 0; i < SC_EPT; ++i) {
            int e = lo + i * THREADS + t;
            int ec = (e < E) ? e : (E - 1);
            srcv[i] = p32[ec];
            dstv[i] = (e < E) ? p32[E + ec] : -1;
        }
    }
    #pragma unroll
    for (int i = 0; i < SC_EPT; ++i)
        if (dstv[i] >= 0) atomicAdd(&h[dstv[i] >> 7], 1);
    __syncthreads();
    for (int i = t; i < B; i += THREADS) {
        int c = h[i];
        base[i] = c ? atomicAdd(&bucket_cursor[i], c) : 0;
    }
    __syncthreads();
    for (int i = t; i < B; i += THREADS) h[i] = 0;
    __syncthreads();
    #pragma unroll
    for (int i = 0; i < SC_EPT; ++i) {
        if (dstv[i] >= 0) {
            int b = dstv[i] >> 7;
            int pos = base[b] + atomicAdd(&h[b], 1);
            packed[pos] = (unsigned int)srcv[i] | ((unsigned int)(dstv[i] & 127) << 25);
        }
    }
}

// One block per bucket; size derived from final cursor. LDS hist/scan/rank over
// <=128 local nodes, staged coalesced csr write; emits offsets/count/dinv.
__global__ void k_fine_sort(const unsigned int* __restrict__ packed,
                            const int* __restrict__ bucket_cursor,
                            int* __restrict__ csr, int* __restrict__ offsets,
                            int* __restrict__ countp, float* __restrict__ dinv,
                            int n, int B) {
    __shared__ unsigned int words[CAP];
    __shared__ int srcstage[CAP];
    __shared__ int cnt[128];
    __shared__ int scanv[128];
    __shared__ int cursor[128];
    int b = blockIdx.x;
    int t = threadIdx.x;
    int base = b << CAPB_LOG;
    int size = bucket_cursor[b] - base;
    if (t < 128) cnt[t] = 0;
    __syncthreads();
    for (int i0 = 0; i0 < size; i0 += THREADS) {
        int i = i0 + t;
        if (i < size) {
            unsigned int w = packed[base + i];
            words[i] = w;
            atomicAdd(&cnt[(w >> 25) & 127], 1);
        }
    }
    __syncthreads();
    if (t < 128) scanv[t] = cnt[t];
    __syncthreads();
    for (int off = 1; off < 128; off <<= 1) {
        int v = 0;
        if (t < 128 && t >= off) v = scanv[t - off];
        __syncthreads();
        if (t < 128) scanv[t] += v;
        __syncthreads();
    }
    if (t < 128) {
        int ex = scanv[t] - cnt[t];
        scanv[t] = ex;
        cursor[t] = ex;
        int node = (b << 7) + t;
        if (node < n) {
            offsets[node] = base + ex;
            countp[node] = cnt[t];
            dinv[node] = rsqrtf((float)(cnt[t] + 1));
        }
    }
    __syncthreads();
    for (int i0 = 0; i0 < size; i0 += THREADS) {
        int i = i0 + t;
        if (i < size) {
            unsigned int w = words[i];
            int d = (w >> 25) & 127;
            int rank = atomicAdd(&cursor[d], 1);
            srcstage[rank] = (int)(w & 0x1FFFFFFu);
        }
    }
    __syncthreads();
    for (int i0 = 0; i0 < size; i0 += THREADS) {
        int i = i0 + t;
        if (i < size) csr[base + i] = srcstage[i];
    }
}

// MFMA gemm1: block = 4 waves = 64 rows; full 64 cols; K=128.
__global__ void __launch_bounds__(THREADS) k_gemm1(const float* __restrict__ x,
                                                   const uint4* __restrict__ w1f,
                                                   const float* __restrict__ dinv,
                                                   unsigned short* __restrict__ hs1, int n) {
    int t = threadIdx.x;
    int w = t >> 6, l = t & 63;
    int rowbase = blockIdx.x * 64 + w * 16;

    uint4 bfr[16];
    #pragma unroll
    for (int f = 0; f < 16; ++f) bfr[f] = w1f[f * 64 + l];

    f32x4 acc[4];
    #pragma unroll
    for (int ct = 0; ct < 4; ++ct) acc[ct] = (f32x4){0.f, 0.f, 0.f, 0.f};

    int arow = rowbase + (l & 15);
    bool rv = (arow < n);
    const float* xp = x + (size_t)arow * 128 + (l >> 4) * 8;

    #pragma unroll
    for (int kt = 0; kt < 4; ++kt) {
        float4 a0 = make_float4(0.f, 0.f, 0.f, 0.f), a1 = a0;
        if (rv) {
            a0 = ((const float4*)(xp + kt * 32))[0];
            a1 = ((const float4*)(xp + kt * 32))[1];
        }
        frag_u af;
        af.u4 = make_uint4(pack_bf2(a0.x, a0.y), pack_bf2(a0.z, a0.w),
                           pack_bf2(a1.x, a1.y), pack_bf2(a1.z, a1.w));
        #pragma unroll
        for (int ct = 0; ct < 4; ++ct) {
            frag_u bfu; bfu.u4 = bfr[ct * 4 + kt];
            acc[ct] = __builtin_amdgcn_mfma_f32_16x16x32_bf16(af.s8, bfu.s8, acc[ct], 0, 0, 0);
        }
    }

    int orow0 = rowbase + (l >> 4) * 4;
    #pragma unroll
    for (int reg = 0; reg < 4; ++reg) {
        int r = orow0 + reg;
        if (r < n) {
            float dv = dinv[r];
            #pragma unroll
            for (int ct = 0; ct < 4; ++ct)
                hs1[(size_t)r * 64 + ct * 16 + (l & 15)] = bf16r(acc[ct][reg] * dv);
        }
    }
}

// agg1 FUSED with gemm2: gather/reduce h1 row -> relu -> LDS -> wave matvec
// vs fp32 W2 (LDS) -> bf16 hs2 row. h1post buffer and gemm2 kernel eliminated.
__global__ void k_agg1_fused(const unsigned int* __restrict__ hs1, const int* __restrict__ csr,
                             const int* __restrict__ offsets, const int* __restrict__ count,
                             const float* __restrict__ dinv, const float* __restrict__ b1,
                             const float* __restrict__ W2,
                             unsigned int* __restrict__ hs2, int n) {
    __shared__ float W2s[64 * 32];       // 8 KB fp32
    __shared__ float h1row[4][64];       // 1 KB
    int t = threadIdx.x;
    #pragma unroll
    for (int i = 0; i < 2; ++i)
        ((float4*)W2s)[t + i * THREADS] = ((const float4*)W2)[t + i * THREADS];

    int wid = t >> 6;
    int lane = t & 63;
    int node = blockIdx.x * 4 + wid;
    bool valid = (node < n);
    int g  = lane >> 4;
    int f4 = lane & 15;
    const uint2* tab = (const uint2*)hs1;

    if (valid) {
        int s = offsets[node];
        int c = count[node];
        float4 a0 = make_float4(0.f, 0.f, 0.f, 0.f);
        float4 a1 = a0, a2 = a0, a3 = a0;
        if (g == 0) {
            uint2 sv = tab[(size_t)node * 16 + f4];
            a0 = make_float4(bf_lo(sv.x), bf_hi(sv.x), bf_lo(sv.y), bf_hi(sv.y));
        }
        for (int j0 = 0; j0 < c; j0 += 64) {
            int cc = min(c - j0, 64);
            int idx = csr[s + j0 + min(lane, cc - 1)];   // one coalesced 64-lane load
            for (int j = 0; j < cc; j += 16) {
                int e0 = j + g, e1 = e0 + 4, e2 = e0 + 8, e3 = e0 + 12;
                int s0 = __shfl(idx, min(e0, cc - 1));
                int s1 = __shfl(idx, min(e1, cc - 1));
                int s2 = __shfl(idx, min(e2, cc - 1));
                int s3 = __shfl(idx, min(e3, cc - 1));
                uint2 u0 = tab[(size_t)s0 * 16 + f4];
                uint2 u1 = tab[(size_t)s1 * 16 + f4];
                uint2 u2 = tab[(size_t)s2 * 16 + f4];
                uint2 u3 = tab[(size_t)s3 * 16 + f4];
                float m0 = (e0 < cc) ? 1.f : 0.f;
                float m1 = (e1 < cc) ? 1.f : 0.f;
                float m2 = (e2 < cc) ? 1.f : 0.f;
                float m3 = (e3 < cc) ? 1.f : 0.f;
                a0.x = fmaf(m0, bf_lo(u0.x), a0.x); a0.y = fmaf(m0, bf_hi(u0.x), a0.y);
                a0.z = fmaf(m0, bf_lo(u0.y), a0.z); a0.w = fmaf(m0, bf_hi(u0.y), a0.w);
                a1.x = fmaf(m1, bf_lo(u1.x), a1.x); a1.y = fmaf(m1, bf_hi(u1.x), a1.y);
                a1.z = fmaf(m1, bf_lo(u1.y), a1.z); a1.w = fmaf(m1, bf_hi(u1.y), a1.w);
                a2.x = fmaf(m2, bf_lo(u2.x), a2.x); a2.y = fmaf(m2, bf_hi(u2.x), a2.y);
                a2.z = fmaf(m2, bf_lo(u2.y), a2.z); a2.w = fmaf(m2, bf_hi(u2.y), a2.w);
                a3.x = fmaf(m3, bf_lo(u3.x), a3.x); a3.y = fmaf(m3, bf_hi(u3.x), a3.y);
                a3.z = fmaf(m3, bf_lo(u3.y), a3.z); a3.w = fmaf(m3, bf_hi(u3.y), a3.w);
            }
        }
        a0.x += a1.x + a2.x + a3.x;
        a0.y += a1.y + a2.y + a3.y;
        a0.z += a1.z + a2.z + a3.z;
        a0.w += a1.w + a2.w + a3.w;
        a0.x += __shfl_xor(a0.x, 16); a0.y += __shfl_xor(a0.y, 16);
        a0.z += __shfl_xor(a0.z, 16); a0.w += __shfl_xor(a0.w, 16);
        a0.x += __shfl_xor(a0.x, 32); a0.y += __shfl_xor(a0.y, 32);
        a0.z += __shfl_xor(a0.z, 32); a0.w += __shfl_xor(a0.w, 32);

        if (g == 0) {
            float dv = dinv[node];
            float4 b = ((const float4*)b1)[f4];
            float ox = fmaxf(fmaf(dv, a0.x, b.x), 0.f);
            float oy = fmaxf(fmaf(dv, a0.y, b.y), 0.f);
            float oz = fmaxf(fmaf(dv, a0.z, b.z), 0.f);
            float ow = fmaxf(fmaf(dv, a0.w, b.w), 0.f);
            ((float4*)h1row[wid])[f4] = make_float4(ox, oy, oz, ow);
        }
    }
    __syncthreads();    // W2s ready + h1row visible across lanes
    if (valid) {
        // lane: col = lane&31, half = lane>>5; p = sum_{k in half} h1[k]*W2[k][col]
        int col = lane & 31, half = lane >> 5;
        const float* hr = h1row[wid] + half * 32;
        const float* wp = W2s + half * 32 * 32 + col;
        float p = 0.f;
        #pragma unroll
        for (int k = 0; k < 32; ++k)
            p = fmaf(hr[k], wp[k * 32], p);
        p += __shfl_xor(p, 32);
        p *= dinv[node];
        float q = __shfl_xor(p, 1);      // partner column
        if (half == 0 && (lane & 1) == 0)
            hs2[(size_t)node * 16 + (lane >> 1)] = pack_bf2(p, q);
    }
}

// One wave per node. 64-wide CSR preload + shfl; 16 edges/iter (8 groups x 2-deep). Fused head.
__global__ void k_agg2_head(const unsigned int* __restrict__ hs2, const int* __restrict__ csr,
                            const int* __restrict__ offsets, const int* __restrict__ count,
                            const float* __restrict__ dinv, const float* __restrict__ b2,
                            const float* __restrict__ Wfc, const float* __restrict__ bfc,
                            float* __restrict__ out, int n) {
    int wid = threadIdx.x >> 6;
    int lane = threadIdx.x & 63;
    int node = blockIdx.x * 4 + wid;
    if (node >= n) return;
    int g  = lane >> 3;
    int f4 = lane & 7;
    int s = offsets[node];
    int c = count[node];
    const uint2* tab = (const uint2*)hs2;

    float4 a0 = make_float4(0.f, 0.f, 0.f, 0.f);
    float4 a1 = a0;
    if (g == 0) {
        uint2 sv = tab[(size_t)node * 8 + f4];
        a0 = make_float4(bf_lo(sv.x), bf_hi(sv.x), bf_lo(sv.y), bf_hi(sv.y));
    }

    for (int j0 = 0; j0 < c; j0 += 64) {
        int cc = min(c - j0, 64);
        int idx = csr[s + j0 + min(lane, cc - 1)];
        for (int j = 0; j < cc; j += 16) {
            int e0 = j + g, e1 = e0 + 8;
            int s0 = __shfl(idx, min(e0, cc - 1));
            int s1 = __shfl(idx, min(e1, cc - 1));
            uint2 u0 = tab[(size_t)s0 * 8 + f4];
            uint2 u1 = tab[(size_t)s1 * 8 + f4];
            float m0 = (e0 < cc) ? 1.f : 0.f;
            float m1 = (e1 < cc) ? 1.f : 0.f;
            a0.x = fmaf(m0, bf_lo(u0.x), a0.x); a0.y = fmaf(m0, bf_hi(u0.x), a0.y);
            a0.z = fmaf(m0, bf_lo(u0.y), a0.z); a0.w = fmaf(m0, bf_hi(u0.y), a0.w);
            a1.x = fmaf(m1, bf_lo(u1.x), a1.x); a1.y = fmaf(m1, bf_hi(u1.x), a1.y);
            a1.z = fmaf(m1, bf_lo(u1.y), a1.z); a1.w = fmaf(m1, bf_hi(u1.y), a1.w);
        }
    }
    a0.x += a1.x; a0.y += a1.y; a0.z += a1.z; a0.w += a1.w;
    #pragma unroll
    for (int m = 8; m <= 32; m <<= 1) {
        a0.x += __shfl_xor(a0.x, m); a0.y += __shfl_xor(a0.y, m);
        a0.z += __shfl_xor(a0.z, m); a0.w += __shfl_xor(a0.w, m);
    }

    float dv = dinv[node];
    float4 b = ((const float4*)b2)[f4];
    float4 w = ((const float4*)Wfc)[f4];
    float hx = fmaxf(fmaf(dv, a0.x, b.x), 0.f);
    float hy = fmaxf(fmaf(dv, a0.y, b.y), 0.f);
    float hz = fmaxf(fmaf(dv, a0.z, b.z), 0.f);
    float hw = fmaxf(fmaf(dv, a0.w, b.w), 0.f);
    float p = hx * w.x + hy * w.y + hz * w.z + hw * w.w;
    p += __shfl_xor(p, 1);
    p += __shfl_xor(p, 2);
    p += __shfl_xor(p, 4);
    if (lane == 0) out[node] = p + bfc[0];
}

extern "C" void kernel_launch(void* const* d_in, const int* in_sizes, int n_in,
                              void* d_out, int out_size, void* d_ws, size_t ws_size,
                              hipStream_t stream) {
    const float* x   = (const float*)d_in[0];
    const void*  ei  = d_in[1];
    const float* W1  = (const float*)d_in[2];
    const float* b1  = (const float*)d_in[3];
    const float* W2  = (const float*)d_in[4];
    const float* b2  = (const float*)d_in[5];
    const float* Wfc = (const float*)d_in[6];
    const float* bfc = (const float*)d_in[7];
    float* out = (float*)d_out;

    const int n = in_sizes[0] / 128;                 // 100000
    const int E = in_sizes[1] / 2;                   // 1600000
    const int B = (n + 127) >> 7;                    // 782 buckets
    const size_t BCAP = (size_t)B << CAPB_LOG;       // fixed-capacity region total

    size_t off = 0;
    auto alloc = [&](size_t bytes) -> void* {
        void* p = (char*)d_ws + off;
        off += (bytes + 255) & ~(size_t)255;
        return p;
    };
    int*   bucket_cursor = (int*)alloc((size_t)NBUCK_MAX * 4);
    unsigned int* packed = (unsigned int*)alloc(BCAP * 4);
    int*   csr     = (int*)  alloc(BCAP * 4);
    int*   offsets = (int*)  alloc((size_t)n * 4);
    int*   count   = (int*)  alloc((size_t)n * 4);
    float* dinv    = (float*)alloc((size_t)n * 4);
    unsigned int* hs1 = (unsigned int*)alloc((size_t)n * 64 * 2);  // bf16
    unsigned int* hs2 = (unsigned int*)alloc((size_t)n * 32 * 2);  // bf16
    uint4* w1f   = (uint4*)alloc(1024 * 16);
    int*   flag  = (int*)  alloc(4);
    (void)ws_size;

    const int GB = (n + 63) / 64;                    // MFMA gemm blocks
    const int AG = (n + 3) / 4;
    const int PREP = 1 + (B + THREADS - 1) / THREADS;
    const int SB = (E + THREADS * SC_EPT - 1) / (THREADS * SC_EPT);   // 391 scatter blocks

    k_prep<<<PREP, THREADS, 0, stream>>>((const unsigned int*)ei, flag, bucket_cursor, B, W1, w1f);
    k_bucket_scatter<<<SB, THREADS, 0, stream>>>(ei, flag, bucket_cursor, packed, E, B);
    k_fine_sort<<<B, THREADS, 0, stream>>>(packed, bucket_cursor, csr, offsets, count, dinv, n, B);
    k_gemm1<<<GB, THREADS, 0, stream>>>(x, w1f, dinv, (unsigned short*)hs1, n);
    k_agg1_fused<<<AG, THREADS, 0, stream>>>(hs1, csr, offsets, count, dinv, b1, W2, hs2, n);
    k_agg2_head<<<AG, THREADS, 0, stream>>>(hs2, csr, offsets, count, dinv, b2, Wfc, bfc, out, n);
}

// Round 13
// 132.116 us; speedup vs baseline: 1.0719x; 1.0719x over previous
//
#include <hip/hip_runtime.h>
#include <hip/hip_bf16.h>
#include <stdint.h>

// GCN 2-layer + linear head. bf16 node tables + MFMA GEMMs (16x16x32 bf16).
// CSR build = fixed-capacity bucket sort (4096/bucket), register-staged
// single-pass scatter. NEW: gemm1 (no dinv prescale) grid-fused with scatter
// (independent: gemm1 needs only x,W1); agg1 folds dinv[src] into its tail
// mask (mask-fma becomes the norm multiply, zero extra VALU).
// agg1 is at its compulsory per-XCD L2-fill floor (FETCH == 8*0.86*table).

#define THREADS 256
#define NBUCK_MAX 1024
#define CAP 4096
#define CAPB_LOG 12          // 4096 entries per bucket, fixed
#define SC_EPT 16            // edges per thread in scatter (4096/block)

typedef __attribute__((ext_vector_type(8))) short short8;
typedef __attribute__((ext_vector_type(4))) float f32x4;
union frag_u { uint4 u4; short8 s8; };

__device__ __forceinline__ unsigned int pack_bf2(float a, float b) {
    unsigned int ua = __float_as_uint(a);
    unsigned int ub = __float_as_uint(b);
    ua = (ua + 0x7FFFu + ((ua >> 16) & 1u)) >> 16;
    ub = (ub + 0x7FFFu + ((ub >> 16) & 1u)) >> 16;
    return ua | (ub << 16);
}
__device__ __forceinline__ unsigned short bf16r(float a) {
    unsigned int ua = __float_as_uint(a);
    return (unsigned short)((ua + 0x7FFFu + ((ua >> 16) & 1u)) >> 16);
}
__device__ __forceinline__ float bf_lo(unsigned int u) { return __uint_as_float(u << 16); }
__device__ __forceinline__ float bf_hi(unsigned int u) { return __uint_as_float(u & 0xFFFF0000u); }

__device__ __forceinline__ int detect64(const unsigned int* w) {
    int is64 = 1;
    #pragma unroll
    for (int i = 1; i < 64; i += 2) {
        if (w[i] != 0u) { is64 = 0; break; }
    }
    return is64;
}

// block 0: dtype flag + pack W1/W2 into MFMA B-frag layout; blocks 1+: init cursors.
__global__ void k_prep(const unsigned int* ei_words, int* flag,
                       int* bucket_cursor, int B,
                       const float* __restrict__ W1, const float* __restrict__ W2,
                       uint4* __restrict__ w1f, uint4* __restrict__ w2f) {
    int b = blockIdx.x;
    int t = threadIdx.x;
    if (b == 0) {
        if (t == 0) *flag = detect64(ei_words);
        // B-frag (16x16x32): lane l, elem e -> B[k][c], k = kt*32+(l>>4)*8+e, c = ct*16+(l&15).
        for (int i = t; i < 1024; i += THREADS) {
            int l = i & 63;
            int f = i >> 6;                 // ct*4 + kt
            int ct = f >> 2, kt = f & 3;
            int c = ct * 16 + (l & 15);
            int k0 = kt * 32 + (l >> 4) * 8;
            unsigned int r0 = pack_bf2(W1[(k0 + 0) * 64 + c], W1[(k0 + 1) * 64 + c]);
            unsigned int r1 = pack_bf2(W1[(k0 + 2) * 64 + c], W1[(k0 + 3) * 64 + c]);
            unsigned int r2 = pack_bf2(W1[(k0 + 4) * 64 + c], W1[(k0 + 5) * 64 + c]);
            unsigned int r3 = pack_bf2(W1[(k0 + 6) * 64 + c], W1[(k0 + 7) * 64 + c]);
            w1f[i] = make_uint4(r0, r1, r2, r3);
        }
        {
            int l = t & 63;
            int f = t >> 6;                 // ct*2 + kt
            int ct = f >> 1, kt = f & 1;
            int c = ct * 16 + (l & 15);
            int k0 = kt * 32 + (l >> 4) * 8;
            unsigned int r0 = pack_bf2(W2[(k0 + 0) * 32 + c], W2[(k0 + 1) * 32 + c]);
            unsigned int r1 = pack_bf2(W2[(k0 + 2) * 32 + c], W2[(k0 + 3) * 32 + c]);
            unsigned int r2 = pack_bf2(W2[(k0 + 4) * 32 + c], W2[(k0 + 5) * 32 + c]);
            unsigned int r3 = pack_bf2(W2[(k0 + 6) * 32 + c], W2[(k0 + 7) * 32 + c]);
            w2f[t] = make_uint4(r0, r1, r2, r3);
        }
    } else {
        int i = (b - 1) * THREADS + t;
        if (i < B) bucket_cursor[i] = i << CAPB_LOG;
    }
}

// Grid-fused: blocks [0,SB) = register-staged scatter; blocks [SB,..) = MFMA gemm1
// (hs1 = bf16(x @ W1), NO dinv prescale). Independent workloads overlap on the CUs.
__global__ void __launch_bounds__(THREADS) k_scatter_gemm1(
        const void* ei, const int* __restrict__ flag,
        int* bucket_cursor, unsigned int* packed, int E, int B, int SB,
        const float* __restrict__ x, const uint4* __restrict__ w1f,
        unsigned short* __restrict__ hs1, int n) {
    __shared__ int h[NBUCK_MAX];
    __shared__ int base[NBUCK_MAX];
    int t = threadIdx.x;

    if ((int)blockIdx.x < SB) {
        // ---- scatter ----
        for (int i = t; i < B; i += THREADS) h[i] = 0;
        bool is64 = (*flag != 0);
        __syncthreads();
        int lo = blockIdx.x * (THREADS * SC_EPT);
        const long long* p64 = (const long long*)ei;
        const int* p32 = (const int*)ei;

        int srcv[SC_EPT], dstv[SC_EPT];
        if (is64) {
            #pragma unroll
            for (int i = 0; i < SC_EPT; ++i) {
                int e = lo + i * THREADS + t;
                int ec = (e < E) ? e : (E - 1);
                srcv[i] = (int)p64[ec];
                dstv[i] = (e < E) ? (int)p64[(size_t)E + ec] : -1;
            }
        } else {
            #pragma unroll
            for (int i = 0; i < SC_EPT; ++i) {
                int e = lo + i * THREADS + t;
                int ec = (e < E) ? e : (E - 1);
                srcv[i] = p32[ec];
                dstv[i] = (e < E) ? p32[E + ec] : -1;
            }
        }
        #pragma unroll
        for (int i = 0; i < SC_EPT; ++i)
            if (dstv[i] >= 0) atomicAdd(&h[dstv[i] >> 7], 1);
        __syncthreads();
        for (int i = t; i < B; i += THREADS) {
            int c = h[i];
            base[i] = c ? atomicAdd(&bucket_cursor[i], c) : 0;
        }
        __syncthreads();
        for (int i = t; i < B; i += THREADS) h[i] = 0;
        __syncthreads();
        #pragma unroll
        for (int i = 0; i < SC_EPT; ++i) {
            if (dstv[i] >= 0) {
                int b = dstv[i] >> 7;
                int pos = base[b] + atomicAdd(&h[b], 1);
                packed[pos] = (unsigned int)srcv[i] | ((unsigned int)(dstv[i] & 127) << 25);
            }
        }
    } else {
        // ---- MFMA gemm1: 4 waves x 16 rows; 64 cols; K=128 ----
        int gb = blockIdx.x - SB;
        int w = t >> 6, l = t & 63;
        int rowbase = gb * 64 + w * 16;

        uint4 bfr[16];
        #pragma unroll
        for (int f = 0; f < 16; ++f) bfr[f] = w1f[f * 64 + l];

        f32x4 acc[4];
        #pragma unroll
        for (int ct = 0; ct < 4; ++ct) acc[ct] = (f32x4){0.f, 0.f, 0.f, 0.f};

        int arow = rowbase + (l & 15);
        bool rv = (arow < n);
        const float* xp = x + (size_t)arow * 128 + (l >> 4) * 8;

        #pragma unroll
        for (int kt = 0; kt < 4; ++kt) {
            float4 a0 = make_float4(0.f, 0.f, 0.f, 0.f), a1 = a0;
            if (rv) {
                a0 = ((const float4*)(xp + kt * 32))[0];
                a1 = ((const float4*)(xp + kt * 32))[1];
            }
            frag_u af;
            af.u4 = make_uint4(pack_bf2(a0.x, a0.y), pack_bf2(a0.z, a0.w),
                               pack_bf2(a1.x, a1.y), pack_bf2(a1.z, a1.w));
            #pragma unroll
            for (int ct = 0; ct < 4; ++ct) {
                frag_u bfu; bfu.u4 = bfr[ct * 4 + kt];
                acc[ct] = __builtin_amdgcn_mfma_f32_16x16x32_bf16(af.s8, bfu.s8, acc[ct], 0, 0, 0);
            }
        }

        int orow0 = rowbase + (l >> 4) * 4;
        #pragma unroll
        for (int reg = 0; reg < 4; ++reg) {
            int r = orow0 + reg;
            if (r < n) {
                #pragma unroll
                for (int ct = 0; ct < 4; ++ct)
                    hs1[(size_t)r * 64 + ct * 16 + (l & 15)] = bf16r(acc[ct][reg]);
            }
        }
    }
}

// One block per bucket; size derived from final cursor. LDS hist/scan/rank over
// <=128 local nodes, staged coalesced csr write; emits offsets/count/dinv.
__global__ void k_fine_sort(const unsigned int* __restrict__ packed,
                            const int* __restrict__ bucket_cursor,
                            int* __restrict__ csr, int* __restrict__ offsets,
                            int* __restrict__ countp, float* __restrict__ dinv,
                            int n, int B) {
    __shared__ unsigned int words[CAP];
    __shared__ int srcstage[CAP];
    __shared__ int cnt[128];
    __shared__ int scanv[128];
    __shared__ int cursor[128];
    int b = blockIdx.x;
    int t = threadIdx.x;
    int base = b << CAPB_LOG;
    int size = bucket_cursor[b] - base;
    if (t < 128) cnt[t] = 0;
    __syncthreads();
    for (int i0 = 0; i0 < size; i0 += THREADS) {
        int i = i0 + t;
        if (i < size) {
            unsigned int w = packed[base + i];
            words[i] = w;
            atomicAdd(&cnt[(w >> 25) & 127], 1);
        }
    }
    __syncthreads();
    if (t < 128) scanv[t] = cnt[t];
    __syncthreads();
    for (int off = 1; off < 128; off <<= 1) {
        int v = 0;
        if (t < 128 && t >= off) v = scanv[t - off];
        __syncthreads();
        if (t < 128) scanv[t] += v;
        __syncthreads();
    }
    if (t < 128) {
        int ex = scanv[t] - cnt[t];
        scanv[t] = ex;
        cursor[t] = ex;
        int node = (b << 7) + t;
        if (node < n) {
            offsets[node] = base + ex;
            countp[node] = cnt[t];
            dinv[node] = rsqrtf((float)(cnt[t] + 1));
        }
    }
    __syncthreads();
    for (int i0 = 0; i0 < size; i0 += THREADS) {
        int i = i0 + t;
        if (i < size) {
            unsigned int w = words[i];
            int d = (w >> 25) & 127;
            int rank = atomicAdd(&cursor[d], 1);
            srcstage[rank] = (int)(w & 0x1FFFFFFu);
        }
    }
    __syncthreads();
    for (int i0 = 0; i0 < size; i0 += THREADS) {
        int i = i0 + t;
        if (i < size) csr[base + i] = srcstage[i];
    }
}

// One wave per node. 64-wide CSR preload + shfl broadcast; 16 edges/iter
// (4 groups x 4-deep). dinv[src] folded into the tail mask (m = e<cc ? dinv : 0).
__global__ void k_agg1(const unsigned int* __restrict__ hs1, const int* __restrict__ csr,
                       const int* __restrict__ offsets, const int* __restrict__ count,
                       const float* __restrict__ dinv, const float* __restrict__ b1,
                       unsigned int* __restrict__ h1post, int n) {
    int wid = threadIdx.x >> 6;
    int lane = threadIdx.x & 63;
    int node = blockIdx.x * 4 + wid;
    if (node >= n) return;
    int g  = lane >> 4;
    int f4 = lane & 15;
    int s = offsets[node];
    int c = count[node];
    float dvn = dinv[node];
    const uint2* tab = (const uint2*)hs1;

    float4 a0 = make_float4(0.f, 0.f, 0.f, 0.f);
    float4 a1 = a0, a2 = a0, a3 = a0;
    if (g == 0) {
        uint2 sv = tab[(size_t)node * 16 + f4];
        a0 = make_float4(dvn * bf_lo(sv.x), dvn * bf_hi(sv.x),
                         dvn * bf_lo(sv.y), dvn * bf_hi(sv.y));
    }

    for (int j0 = 0; j0 < c; j0 += 64) {
        int cc = min(c - j0, 64);
        int idx = csr[s + j0 + min(lane, cc - 1)];   // one coalesced 64-lane load
        for (int j = 0; j < cc; j += 16) {
            int e0 = j + g, e1 = e0 + 4, e2 = e0 + 8, e3 = e0 + 12;
            int s0 = __shfl(idx, min(e0, cc - 1));
            int s1 = __shfl(idx, min(e1, cc - 1));
            int s2 = __shfl(idx, min(e2, cc - 1));
            int s3 = __shfl(idx, min(e3, cc - 1));
            float m0 = (e0 < cc) ? dinv[s0] : 0.f;   // norm multiply == tail mask
            float m1 = (e1 < cc) ? dinv[s1] : 0.f;
            float m2 = (e2 < cc) ? dinv[s2] : 0.f;
            float m3 = (e3 < cc) ? dinv[s3] : 0.f;
            uint2 u0 = tab[(size_t)s0 * 16 + f4];
            uint2 u1 = tab[(size_t)s1 * 16 + f4];
            uint2 u2 = tab[(size_t)s2 * 16 + f4];
            uint2 u3 = tab[(size_t)s3 * 16 + f4];
            a0.x = fmaf(m0, bf_lo(u0.x), a0.x); a0.y = fmaf(m0, bf_hi(u0.x), a0.y);
            a0.z = fmaf(m0, bf_lo(u0.y), a0.z); a0.w = fmaf(m0, bf_hi(u0.y), a0.w);
            a1.x = fmaf(m1, bf_lo(u1.x), a1.x); a1.y = fmaf(m1, bf_hi(u1.x), a1.y);
            a1.z = fmaf(m1, bf_lo(u1.y), a1.z); a1.w = fmaf(m1, bf_hi(u1.y), a1.w);
            a2.x = fmaf(m2, bf_lo(u2.x), a2.x); a2.y = fmaf(m2, bf_hi(u2.x), a2.y);
            a2.z = fmaf(m2, bf_lo(u2.y), a2.z); a2.w = fmaf(m2, bf_hi(u2.y), a2.w);
            a3.x = fmaf(m3, bf_lo(u3.x), a3.x); a3.y = fmaf(m3, bf_hi(u3.x), a3.y);
            a3.z = fmaf(m3, bf_lo(u3.y), a3.z); a3.w = fmaf(m3, bf_hi(u3.y), a3.w);
        }
    }
    a0.x += a1.x + a2.x + a3.x;
    a0.y += a1.y + a2.y + a3.y;
    a0.z += a1.z + a2.z + a3.z;
    a0.w += a1.w + a2.w + a3.w;
    a0.x += __shfl_xor(a0.x, 16); a0.y += __shfl_xor(a0.y, 16);
    a0.z += __shfl_xor(a0.z, 16); a0.w += __shfl_xor(a0.w, 16);
    a0.x += __shfl_xor(a0.x, 32); a0.y += __shfl_xor(a0.y, 32);
    a0.z += __shfl_xor(a0.z, 32); a0.w += __shfl_xor(a0.w, 32);

    if (g == 0) {
        float4 b = ((const float4*)b1)[f4];
        float ox = fmaxf(fmaf(dvn, a0.x, b.x), 0.f);
        float oy = fmaxf(fmaf(dvn, a0.y, b.y), 0.f);
        float oz = fmaxf(fmaf(dvn, a0.z, b.z), 0.f);
        float ow = fmaxf(fmaf(dvn, a0.w, b.w), 0.f);
        uint2 o;
        o.x = pack_bf2(ox, oy);
        o.y = pack_bf2(oz, ow);
        ((uint2*)h1post)[(size_t)node * 16 + f4] = o;
    }
}

// MFMA gemm2: block = 4 waves = 64 rows; 32 cols; K=64. A = h1post (bf16).
__global__ void __launch_bounds__(THREADS) k_gemm2(const uint4* __restrict__ h1,
                                                   const uint4* __restrict__ w2f,
                                                   const float* __restrict__ dinv,
                                                   unsigned short* __restrict__ hs2, int n) {
    int t = threadIdx.x;
    int w = t >> 6, l = t & 63;
    int rowbase = blockIdx.x * 64 + w * 16;

    uint4 bfr[4];
    #pragma unroll
    for (int f = 0; f < 4; ++f) bfr[f] = w2f[f * 64 + l];

    f32x4 acc[2];
    acc[0] = (f32x4){0.f, 0.f, 0.f, 0.f};
    acc[1] = (f32x4){0.f, 0.f, 0.f, 0.f};

    int arow = rowbase + (l & 15);
    bool rv = (arow < n);
    const uint4* hp = h1 + (size_t)arow * 8 + (l >> 4);

    #pragma unroll
    for (int kt = 0; kt < 2; ++kt) {
        frag_u af;
        af.u4 = rv ? hp[kt * 4] : make_uint4(0u, 0u, 0u, 0u);
        #pragma unroll
        for (int ct = 0; ct < 2; ++ct) {
            frag_u bfu; bfu.u4 = bfr[ct * 2 + kt];
            acc[ct] = __builtin_amdgcn_mfma_f32_16x16x32_bf16(af.s8, bfu.s8, acc[ct], 0, 0, 0);
        }
    }

    int orow0 = rowbase + (l >> 4) * 4;
    #pragma unroll
    for (int reg = 0; reg < 4; ++reg) {
        int r = orow0 + reg;
        if (r < n) {
            float dv = dinv[r];
            #pragma unroll
            for (int ct = 0; ct < 2; ++ct)
                hs2[(size_t)r * 32 + ct * 16 + (l & 15)] = bf16r(acc[ct][reg] * dv);
        }
    }
}

// One wave per node. 64-wide CSR preload + shfl; 16 edges/iter (8 groups x 2-deep). Fused head.
__global__ void k_agg2_head(const unsigned int* __restrict__ hs2, const int* __restrict__ csr,
                            const int* __restrict__ offsets, const int* __restrict__ count,
                            const float* __restrict__ dinv, const float* __restrict__ b2,
                            const float* __restrict__ Wfc, const float* __restrict__ bfc,
                            float* __restrict__ out, int n) {
    int wid = threadIdx.x >> 6;
    int lane = threadIdx.x & 63;
    int node = blockIdx.x * 4 + wid;
    if (node >= n) return;
    int g  = lane >> 3;
    int f4 = lane & 7;
    int s = offsets[node];
    int c = count[node];
    const uint2* tab = (const uint2*)hs2;

    float4 a0 = make_float4(0.f, 0.f, 0.f, 0.f);
    float4 a1 = a0;
    if (g == 0) {
        uint2 sv = tab[(size_t)node * 8 + f4];
        a0 = make_float4(bf_lo(sv.x), bf_hi(sv.x), bf_lo(sv.y), bf_hi(sv.y));
    }

    for (int j0 = 0; j0 < c; j0 += 64) {
        int cc = min(c - j0, 64);
        int idx = csr[s + j0 + min(lane, cc - 1)];
        for (int j = 0; j < cc; j += 16) {
            int e0 = j + g, e1 = e0 + 8;
            int s0 = __shfl(idx, min(e0, cc - 1));
            int s1 = __shfl(idx, min(e1, cc - 1));
            uint2 u0 = tab[(size_t)s0 * 8 + f4];
            uint2 u1 = tab[(size_t)s1 * 8 + f4];
            float m0 = (e0 < cc) ? 1.f : 0.f;
            float m1 = (e1 < cc) ? 1.f : 0.f;
            a0.x = fmaf(m0, bf_lo(u0.x), a0.x); a0.y = fmaf(m0, bf_hi(u0.x), a0.y);
            a0.z = fmaf(m0, bf_lo(u0.y), a0.z); a0.w = fmaf(m0, bf_hi(u0.y), a0.w);
            a1.x = fmaf(m1, bf_lo(u1.x), a1.x); a1.y = fmaf(m1, bf_hi(u1.x), a1.y);
            a1.z = fmaf(m1, bf_lo(u1.y), a1.z); a1.w = fmaf(m1, bf_hi(u1.y), a1.w);
        }
    }
    a0.x += a1.x; a0.y += a1.y; a0.z += a1.z; a0.w += a1.w;
    #pragma unroll
    for (int m = 8; m <= 32; m <<= 1) {
        a0.x += __shfl_xor(a0.x, m); a0.y += __shfl_xor(a0.y, m);
        a0.z += __shfl_xor(a0.z, m); a0.w += __shfl_xor(a0.w, m);
    }

    float dv = dinv[node];
    float4 b = ((const float4*)b2)[f4];
    float4 w = ((const float4*)Wfc)[f4];
    float hx = fmaxf(fmaf(dv, a0.x, b.x), 0.f);
    float hy = fmaxf(fmaf(dv, a0.y, b.y), 0.f);
    float hz = fmaxf(fmaf(dv, a0.z, b.z), 0.f);
    float hw = fmaxf(fmaf(dv, a0.w, b.w), 0.f);
    float p = hx * w.x + hy * w.y + hz * w.z + hw * w.w;
    p += __shfl_xor(p, 1);
    p += __shfl_xor(p, 2);
    p += __shfl_xor(p, 4);
    if (lane == 0) out[node] = p + bfc[0];
}

extern "C" void kernel_launch(void* const* d_in, const int* in_sizes, int n_in,
                              void* d_out, int out_size, void* d_ws, size_t ws_size,
                              hipStream_t stream) {
    const float* x   = (const float*)d_in[0];
    const void*  ei  = d_in[1];
    const float* W1  = (const float*)d_in[2];
    const float* b1  = (const float*)d_in[3];
    const float* W2  = (const float*)d_in[4];
    const float* b2  = (const float*)d_in[5];
    const float* Wfc = (const float*)d_in[6];
    const float* bfc = (const float*)d_in[7];
    float* out = (float*)d_out;

    const int n = in_sizes[0] / 128;                 // 100000
    const int E = in_sizes[1] / 2;                   // 1600000
    const int B = (n + 127) >> 7;                    // 782 buckets
    const size_t BCAP = (size_t)B << CAPB_LOG;       // fixed-capacity region total

    size_t off = 0;
    auto alloc = [&](size_t bytes) -> void* {
        void* p = (char*)d_ws + off;
        off += (bytes + 255) & ~(size_t)255;
        return p;
    };
    int*   bucket_cursor = (int*)alloc((size_t)NBUCK_MAX * 4);
    unsigned int* packed = (unsigned int*)alloc(BCAP * 4);
    int*   csr     = (int*)  alloc(BCAP * 4);
    int*   offsets = (int*)  alloc((size_t)n * 4);
    int*   count   = (int*)  alloc((size_t)n * 4);
    float* dinv    = (float*)alloc((size_t)n * 4);
    unsigned int* hs1    = (unsigned int*)alloc((size_t)n * 64 * 2);  // bf16
    unsigned int* h1post = (unsigned int*)alloc((size_t)n * 64 * 2);  // bf16
    unsigned int* hs2    = (unsigned int*)alloc((size_t)n * 32 * 2);  // bf16
    uint4* w1f   = (uint4*)alloc(1024 * 16);
    uint4* w2f   = (uint4*)alloc(256 * 16);
    int*   flag  = (int*)  alloc(4);
    (void)ws_size;

    const int GB = (n + 63) / 64;                    // MFMA gemm blocks (1563)
    const int AG = (n + 3) / 4;
    const int PREP = 1 + (B + THREADS - 1) / THREADS;
    const int SB = (E + THREADS * SC_EPT - 1) / (THREADS * SC_EPT);   // 391 scatter blocks

    k_prep<<<PREP, THREADS, 0, stream>>>((const unsigned int*)ei, flag, bucket_cursor, B,
                                         W1, W2, w1f, w2f);
    k_scatter_gemm1<<<SB + GB, THREADS, 0, stream>>>(ei, flag, bucket_cursor, packed, E, B, SB,
                                                     x, w1f, (unsigned short*)hs1, n);
    k_fine_sort<<<B, THREADS, 0, stream>>>(packed, bucket_cursor, csr, offsets, count, dinv, n, B);
    k_agg1<<<AG, THREADS, 0, stream>>>(hs1, csr, offsets, count, dinv, b1, h1post, n);
    k_gemm2<<<GB, THREADS, 0, stream>>>((const uint4*)h1post, w2f, dinv, (unsigned short*)hs2, n);
    k_agg2_head<<<AG, THREADS, 0, stream>>>(hs2, csr, offsets, count, dinv, b2, Wfc, bfc, out, n);
}

// Round 16
// 131.973 us; speedup vs baseline: 1.0730x; 1.0011x over previous
//
#include <hip/hip_runtime.h>
#include <hip/hip_bf16.h>
#include <stdint.h>

// GCN 2-layer + linear head. bf16 node tables + MFMA GEMMs (16x16x32 bf16).
// CSR build = fixed-capacity bucket sort (4096/bucket), register-staged
// single-pass scatter grid-fused with gemm1 (no dinv prescale). agg1 folds
// dinv[src] into the tail mask via scattered dinv[s] loads.
// NOTE (round-14/15 lesson): do NOT move the dinv lookup to a shfl inside the
// divergent ternary -- predicated ds_bpermute reads from EXEC-inactive source
// lanes are undefined on CDNA. __shfl(idx,...) here is unconditional => safe.
// NOTE (round-14 lesson): csr segment ordering is numerics-relevant (bf16
// table rounding); keep fine_sort's single-cursor rank pass exactly as-is.
// agg1 is at its compulsory per-XCD L2-fill floor (FETCH == 8*0.86*table).

#define THREADS 256
#define NBUCK_MAX 1024
#define CAP 4096
#define CAPB_LOG 12          // 4096 entries per bucket, fixed
#define SC_EPT 16            // edges per thread in scatter (4096/block)

typedef __attribute__((ext_vector_type(8))) short short8;
typedef __attribute__((ext_vector_type(4))) float f32x4;
union frag_u { uint4 u4; short8 s8; };

__device__ __forceinline__ unsigned int pack_bf2(float a, float b) {
    unsigned int ua = __float_as_uint(a);
    unsigned int ub = __float_as_uint(b);
    ua = (ua + 0x7FFFu + ((ua >> 16) & 1u)) >> 16;
    ub = (ub + 0x7FFFu + ((ub >> 16) & 1u)) >> 16;
    return ua | (ub << 16);
}
__device__ __forceinline__ unsigned short bf16r(float a) {
    unsigned int ua = __float_as_uint(a);
    return (unsigned short)((ua + 0x7FFFu + ((ua >> 16) & 1u)) >> 16);
}
__device__ __forceinline__ float bf_lo(unsigned int u) { return __uint_as_float(u << 16); }
__device__ __forceinline__ float bf_hi(unsigned int u) { return __uint_as_float(u & 0xFFFF0000u); }

__device__ __forceinline__ int detect64(const unsigned int* w) {
    int is64 = 1;
    #pragma unroll
    for (int i = 1; i < 64; i += 2) {
        if (w[i] != 0u) { is64 = 0; break; }
    }
    return is64;
}

// block 0: dtype flag + pack W1/W2 into MFMA B-frag layout; blocks 1+: init cursors.
__global__ void k_prep(const unsigned int* ei_words, int* flag,
                       int* bucket_cursor, int B,
                       const float* __restrict__ W1, const float* __restrict__ W2,
                       uint4* __restrict__ w1f, uint4* __restrict__ w2f) {
    int b = blockIdx.x;
    int t = threadIdx.x;
    if (b == 0) {
        if (t == 0) *flag = detect64(ei_words);
        // B-frag (16x16x32): lane l, elem e -> B[k][c], k = kt*32+(l>>4)*8+e, c = ct*16+(l&15).
        for (int i = t; i < 1024; i += THREADS) {
            int l = i & 63;
            int f = i >> 6;                 // ct*4 + kt
            int ct = f >> 2, kt = f & 3;
            int c = ct * 16 + (l & 15);
            int k0 = kt * 32 + (l >> 4) * 8;
            unsigned int r0 = pack_bf2(W1[(k0 + 0) * 64 + c], W1[(k0 + 1) * 64 + c]);
            unsigned int r1 = pack_bf2(W1[(k0 + 2) * 64 + c], W1[(k0 + 3) * 64 + c]);
            unsigned int r2 = pack_bf2(W1[(k0 + 4) * 64 + c], W1[(k0 + 5) * 64 + c]);
            unsigned int r3 = pack_bf2(W1[(k0 + 6) * 64 + c], W1[(k0 + 7) * 64 + c]);
            w1f[i] = make_uint4(r0, r1, r2, r3);
        }
        {
            int l = t & 63;
            int f = t >> 6;                 // ct*2 + kt
            int ct = f >> 1, kt = f & 1;
            int c = ct * 16 + (l & 15);
            int k0 = kt * 32 + (l >> 4) * 8;
            unsigned int r0 = pack_bf2(W2[(k0 + 0) * 32 + c], W2[(k0 + 1) * 32 + c]);
            unsigned int r1 = pack_bf2(W2[(k0 + 2) * 32 + c], W2[(k0 + 3) * 32 + c]);
            unsigned int r2 = pack_bf2(W2[(k0 + 4) * 32 + c], W2[(k0 + 5) * 32 + c]);
            unsigned int r3 = pack_bf2(W2[(k0 + 6) * 32 + c], W2[(k0 + 7) * 32 + c]);
            w2f[t] = make_uint4(r0, r1, r2, r3);
        }
    } else {
        int i = (b - 1) * THREADS + t;
        if (i < B) bucket_cursor[i] = i << CAPB_LOG;
    }
}

// Grid-fused: blocks [0,SB) = register-staged scatter; blocks [SB,..) = MFMA gemm1
// (hs1 = bf16(x @ W1), NO dinv prescale). Independent workloads overlap on the CUs.
__global__ void __launch_bounds__(THREADS) k_scatter_gemm1(
        const void* ei, const int* __restrict__ flag,
        int* bucket_cursor, unsigned int* packed, int E, int B, int SB,
        const float* __restrict__ x, const uint4* __restrict__ w1f,
        unsigned short* __restrict__ hs1, int n) {
    __shared__ int h[NBUCK_MAX];
    __shared__ int base[NBUCK_MAX];
    int t = threadIdx.x;

    if ((int)blockIdx.x < SB) {
        // ---- scatter ----
        for (int i = t; i < B; i += THREADS) h[i] = 0;
        bool is64 = (*flag != 0);
        __syncthreads();
        int lo = blockIdx.x * (THREADS * SC_EPT);
        const long long* p64 = (const long long*)ei;
        const int* p32 = (const int*)ei;

        int srcv[SC_EPT], dstv[SC_EPT];
        if (is64) {
            #pragma unroll
            for (int i = 0; i < SC_EPT; ++i) {
                int e = lo + i * THREADS + t;
                int ec = (e < E) ? e : (E - 1);
                srcv[i] = (int)p64[ec];
                dstv[i] = (e < E) ? (int)p64[(size_t)E + ec] : -1;
            }
        } else {
            #pragma unroll
            for (int i = 0; i < SC_EPT; ++i) {
                int e = lo + i * THREADS + t;
                int ec = (e < E) ? e : (E - 1);
                srcv[i] = p32[ec];
                dstv[i] = (e < E) ? p32[E + ec] : -1;
            }
        }
        #pragma unroll
        for (int i = 0; i < SC_EPT; ++i)
            if (dstv[i] >= 0) atomicAdd(&h[dstv[i] >> 7], 1);
        __syncthreads();
        for (int i = t; i < B; i += THREADS) {
            int c = h[i];
            base[i] = c ? atomicAdd(&bucket_cursor[i], c) : 0;
        }
        __syncthreads();
        for (int i = t; i < B; i += THREADS) h[i] = 0;
        __syncthreads();
        #pragma unroll
        for (int i = 0; i < SC_EPT; ++i) {
            if (dstv[i] >= 0) {
                int b = dstv[i] >> 7;
                int pos = base[b] + atomicAdd(&h[b], 1);
                packed[pos] = (unsigned int)srcv[i] | ((unsigned int)(dstv[i] & 127) << 25);
            }
        }
    } else {
        // ---- MFMA gemm1: 4 waves x 16 rows; 64 cols; K=128 ----
        int gb = blockIdx.x - SB;
        int w = t >> 6, l = t & 63;
        int rowbase = gb * 64 + w * 16;

        uint4 bfr[16];
        #pragma unroll
        for (int f = 0; f < 16; ++f) bfr[f] = w1f[f * 64 + l];

        f32x4 acc[4];
        #pragma unroll
        for (int ct = 0; ct < 4; ++ct) acc[ct] = (f32x4){0.f, 0.f, 0.f, 0.f};

        int arow = rowbase + (l & 15);
        bool rv = (arow < n);
        const float* xp = x + (size_t)arow * 128 + (l >> 4) * 8;

        #pragma unroll
        for (int kt = 0; kt < 4; ++kt) {
            float4 a0 = make_float4(0.f, 0.f, 0.f, 0.f), a1 = a0;
            if (rv) {
                a0 = ((const float4*)(xp + kt * 32))[0];
                a1 = ((const float4*)(xp + kt * 32))[1];
            }
            frag_u af;
            af.u4 = make_uint4(pack_bf2(a0.x, a0.y), pack_bf2(a0.z, a0.w),
                               pack_bf2(a1.x, a1.y), pack_bf2(a1.z, a1.w));
            #pragma unroll
            for (int ct = 0; ct < 4; ++ct) {
                frag_u bfu; bfu.u4 = bfr[ct * 4 + kt];
                acc[ct] = __builtin_amdgcn_mfma_f32_16x16x32_bf16(af.s8, bfu.s8, acc[ct], 0, 0, 0);
            }
        }

        int orow0 = rowbase + (l >> 4) * 4;
        #pragma unroll
        for (int reg = 0; reg < 4; ++reg) {
            int r = orow0 + reg;
            if (r < n) {
                #pragma unroll
                for (int ct = 0; ct < 4; ++ct)
                    hs1[(size_t)r * 64 + ct * 16 + (l & 15)] = bf16r(acc[ct][reg]);
            }
        }
    }
}

// One block per bucket; size derived from final cursor. LDS hist/scan/rank over
// <=128 local nodes, staged coalesced csr write; emits offsets/count/dinv.
__global__ void k_fine_sort(const unsigned int* __restrict__ packed,
                            const int* __restrict__ bucket_cursor,
                            int* __restrict__ csr, int* __restrict__ offsets,
                            int* __restrict__ countp, float* __restrict__ dinv,
                            int n, int B) {
    __shared__ unsigned int words[CAP];
    __shared__ int srcstage[CAP];
    __shared__ int cnt[128];
    __shared__ int scanv[128];
    __shared__ int cursor[128];
    int b = blockIdx.x;
    int t = threadIdx.x;
    int base = b << CAPB_LOG;
    int size = bucket_cursor[b] - base;
    if (t < 128) cnt[t] = 0;
    __syncthreads();
    for (int i0 = 0; i0 < size; i0 += THREADS) {
        int i = i0 + t;
        if (i < size) {
            unsigned int w = packed[base + i];
            words[i] = w;
            atomicAdd(&cnt[(w >> 25) & 127], 1);
        }
    }
    __syncthreads();
    if (t < 128) scanv[t] = cnt[t];
    __syncthreads();
    for (int off = 1; off < 128; off <<= 1) {
        int v = 0;
        if (t < 128 && t >= off) v = scanv[t - off];
        __syncthreads();
        if (t < 128) scanv[t] += v;
        __syncthreads();
    }
    if (t < 128) {
        int ex = scanv[t] - cnt[t];
        scanv[t] = ex;
        cursor[t] = ex;
        int node = (b << 7) + t;
        if (node < n) {
            offsets[node] = base + ex;
            countp[node] = cnt[t];
            dinv[node] = rsqrtf((float)(cnt[t] + 1));
        }
    }
    __syncthreads();
    for (int i0 = 0; i0 < size; i0 += THREADS) {
        int i = i0 + t;
        if (i < size) {
            unsigned int w = words[i];
            int d = (w >> 25) & 127;
            int rank = atomicAdd(&cursor[d], 1);
            srcstage[rank] = (int)(w & 0x1FFFFFFu);
        }
    }
    __syncthreads();
    for (int i0 = 0; i0 < size; i0 += THREADS) {
        int i = i0 + t;
        if (i < size) csr[base + i] = srcstage[i];
    }
}

// One wave per node. 64-wide CSR preload + shfl broadcast (unconditional shfl,
// all lanes active); 16 edges/iter (4 groups x 4-deep). dinv[src] folded into
// the tail mask via scattered loads (m = e<cc ? dinv[s] : 0).
__global__ void k_agg1(const unsigned int* __restrict__ hs1, const int* __restrict__ csr,
                       const int* __restrict__ offsets, const int* __restrict__ count,
                       const float* __restrict__ dinv, const float* __restrict__ b1,
                       unsigned int* __restrict__ h1post, int n) {
    int wid = threadIdx.x >> 6;
    int lane = threadIdx.x & 63;
    int node = blockIdx.x * 4 + wid;
    if (node >= n) return;
    int g  = lane >> 4;
    int f4 = lane & 15;
    int s = offsets[node];
    int c = count[node];
    float dvn = dinv[node];
    const uint2* tab = (const uint2*)hs1;

    float4 a0 = make_float4(0.f, 0.f, 0.f, 0.f);
    float4 a1 = a0, a2 = a0, a3 = a0;
    if (g == 0) {
        uint2 sv = tab[(size_t)node * 16 + f4];
        a0 = make_float4(dvn * bf_lo(sv.x), dvn * bf_hi(sv.x),
                         dvn * bf_lo(sv.y), dvn * bf_hi(sv.y));
    }

    for (int j0 = 0; j0 < c; j0 += 64) {
        int cc = min(c - j0, 64);
        int idx = csr[s + j0 + min(lane, cc - 1)];   // one coalesced 64-lane load
        for (int j = 0; j < cc; j += 16) {
            int e0 = j + g, e1 = e0 + 4, e2 = e0 + 8, e3 = e0 + 12;
            int s0 = __shfl(idx, min(e0, cc - 1));
            int s1 = __shfl(idx, min(e1, cc - 1));
            int s2 = __shfl(idx, min(e2, cc - 1));
            int s3 = __shfl(idx, min(e3, cc - 1));
            float m0 = (e0 < cc) ? dinv[s0] : 0.f;   // norm multiply == tail mask
            float m1 = (e1 < cc) ? dinv[s1] : 0.f;
            float m2 = (e2 < cc) ? dinv[s2] : 0.f;
            float m3 = (e3 < cc) ? dinv[s3] : 0.f;
            uint2 u0 = tab[(size_t)s0 * 16 + f4];
            uint2 u1 = tab[(size_t)s1 * 16 + f4];
            uint2 u2 = tab[(size_t)s2 * 16 + f4];
            uint2 u3 = tab[(size_t)s3 * 16 + f4];
            a0.x = fmaf(m0, bf_lo(u0.x), a0.x); a0.y = fmaf(m0, bf_hi(u0.x), a0.y);
            a0.z = fmaf(m0, bf_lo(u0.y), a0.z); a0.w = fmaf(m0, bf_hi(u0.y), a0.w);
            a1.x = fmaf(m1, bf_lo(u1.x), a1.x); a1.y = fmaf(m1, bf_hi(u1.x), a1.y);
            a1.z = fmaf(m1, bf_lo(u1.y), a1.z); a1.w = fmaf(m1, bf_hi(u1.y), a1.w);
            a2.x = fmaf(m2, bf_lo(u2.x), a2.x); a2.y = fmaf(m2, bf_hi(u2.x), a2.y);
            a2.z = fmaf(m2, bf_lo(u2.y), a2.z); a2.w = fmaf(m2, bf_hi(u2.y), a2.w);
            a3.x = fmaf(m3, bf_lo(u3.x), a3.x); a3.y = fmaf(m3, bf_hi(u3.x), a3.y);
            a3.z = fmaf(m3, bf_lo(u3.y), a3.z); a3.w = fmaf(m3, bf_hi(u3.y), a3.w);
        }
    }
    a0.x += a1.x + a2.x + a3.x;
    a0.y += a1.y + a2.y + a3.y;
    a0.z += a1.z + a2.z + a3.z;
    a0.w += a1.w + a2.w + a3.w;
    a0.x += __shfl_xor(a0.x, 16); a0.y += __shfl_xor(a0.y, 16);
    a0.z += __shfl_xor(a0.z, 16); a0.w += __shfl_xor(a0.w, 16);
    a0.x += __shfl_xor(a0.x, 32); a0.y += __shfl_xor(a0.y, 32);
    a0.z += __shfl_xor(a0.z, 32); a0.w += __shfl_xor(a0.w, 32);

    if (g == 0) {
        float4 b = ((const float4*)b1)[f4];
        float ox = fmaxf(fmaf(dvn, a0.x, b.x), 0.f);
        float oy = fmaxf(fmaf(dvn, a0.y, b.y), 0.f);
        float oz = fmaxf(fmaf(dvn, a0.z, b.z), 0.f);
        float ow = fmaxf(fmaf(dvn, a0.w, b.w), 0.f);
        uint2 o;
        o.x = pack_bf2(ox, oy);
        o.y = pack_bf2(oz, ow);
        ((uint2*)h1post)[(size_t)node * 16 + f4] = o;
    }
}

// MFMA gemm2: block = 4 waves = 64 rows; 32 cols; K=64. A = h1post (bf16).
__global__ void __launch_bounds__(THREADS) k_gemm2(const uint4* __restrict__ h1,
                                                   const uint4* __restrict__ w2f,
                                                   const float* __restrict__ dinv,
                                                   unsigned short* __restrict__ hs2, int n) {
    int t = threadIdx.x;
    int w = t >> 6, l = t & 63;
    int rowbase = blockIdx.x * 64 + w * 16;

    uint4 bfr[4];
    #pragma unroll
    for (int f = 0; f < 4; ++f) bfr[f] = w2f[f * 64 + l];

    f32x4 acc[2];
    acc[0] = (f32x4){0.f, 0.f, 0.f, 0.f};
    acc[1] = (f32x4){0.f, 0.f, 0.f, 0.f};

    int arow = rowbase + (l & 15);
    bool rv = (arow < n);
    const uint4* hp = h1 + (size_t)arow * 8 + (l >> 4);

    #pragma unroll
    for (int kt = 0; kt < 2; ++kt) {
        frag_u af;
        af.u4 = rv ? hp[kt * 4] : make_uint4(0u, 0u, 0u, 0u);
        #pragma unroll
        for (int ct = 0; ct < 2; ++ct) {
            frag_u bfu; bfu.u4 = bfr[ct * 2 + kt];
            acc[ct] = __builtin_amdgcn_mfma_f32_16x16x32_bf16(af.s8, bfu.s8, acc[ct], 0, 0, 0);
        }
    }

    int orow0 = rowbase + (l >> 4) * 4;
    #pragma unroll
    for (int reg = 0; reg < 4; ++reg) {
        int r = orow0 + reg;
        if (r < n) {
            float dv = dinv[r];
            #pragma unroll
            for (int ct = 0; ct < 2; ++ct)
                hs2[(size_t)r * 32 + ct * 16 + (l & 15)] = bf16r(acc[ct][reg] * dv);
        }
    }
}

// One wave per node. 64-wide CSR preload + shfl; 16 edges/iter (8 groups x 2-deep). Fused head.
__global__ void k_agg2_head(const unsigned int* __restrict__ hs2, const int* __restrict__ csr,
                            const int* __restrict__ offsets, const int* __restrict__ count,
                            const float* __restrict__ dinv, const float* __restrict__ b2,
                            const float* __restrict__ Wfc, const float* __restrict__ bfc,
                            float* __restrict__ out, int n) {
    int wid = threadIdx.x >> 6;
    int lane = threadIdx.x & 63;
    int node = blockIdx.x * 4 + wid;
    if (node >= n) return;
    int g  = lane >> 3;
    int f4 = lane & 7;
    int s = offsets[node];
    int c = count[node];
    const uint2* tab = (const uint2*)hs2;

    float4 a0 = make_float4(0.f, 0.f, 0.f, 0.f);
    float4 a1 = a0;
    if (g == 0) {
        uint2 sv = tab[(size_t)node * 8 + f4];
        a0 = make_float4(bf_lo(sv.x), bf_hi(sv.x), bf_lo(sv.y), bf_hi(sv.y));
    }

    for (int j0 = 0; j0 < c; j0 += 64) {
        int cc = min(c - j0, 64);
        int idx = csr[s + j0 + min(lane, cc - 1)];
        for (int j = 0; j < cc; j += 16) {
            int e0 = j + g, e1 = e0 + 8;
            int s0 = __shfl(idx, min(e0, cc - 1));
            int s1 = __shfl(idx, min(e1, cc - 1));
            uint2 u0 = tab[(size_t)s0 * 8 + f4];
            uint2 u1 = tab[(size_t)s1 * 8 + f4];
            float m0 = (e0 < cc) ? 1.f : 0.f;
            float m1 = (e1 < cc) ? 1.f : 0.f;
            a0.x = fmaf(m0, bf_lo(u0.x), a0.x); a0.y = fmaf(m0, bf_hi(u0.x), a0.y);
            a0.z = fmaf(m0, bf_lo(u0.y), a0.z); a0.w = fmaf(m0, bf_hi(u0.y), a0.w);
            a1.x = fmaf(m1, bf_lo(u1.x), a1.x); a1.y = fmaf(m1, bf_hi(u1.x), a1.y);
            a1.z = fmaf(m1, bf_lo(u1.y), a1.z); a1.w = fmaf(m1, bf_hi(u1.y), a1.w);
        }
    }
    a0.x += a1.x; a0.y += a1.y; a0.z += a1.z; a0.w += a1.w;
    #pragma unroll
    for (int m = 8; m <= 32; m <<= 1) {
        a0.x += __shfl_xor(a0.x, m); a0.y += __shfl_xor(a0.y, m);
        a0.z += __shfl_xor(a0.z, m); a0.w += __shfl_xor(a0.w, m);
    }

    float dv = dinv[node];
    float4 b = ((const float4*)b2)[f4];
    float4 w = ((const float4*)Wfc)[f4];
    float hx = fmaxf(fmaf(dv, a0.x, b.x), 0.f);
    float hy = fmaxf(fmaf(dv, a0.y, b.y), 0.f);
    float hz = fmaxf(fmaf(dv, a0.z, b.z), 0.f);
    float hw = fmaxf(fmaf(dv, a0.w, b.w), 0.f);
    float p = hx * w.x + hy * w.y + hz * w.z + hw * w.w;
    p += __shfl_xor(p, 1);
    p += __shfl_xor(p, 2);
    p += __shfl_xor(p, 4);
    if (lane == 0) out[node] = p + bfc[0];
}

extern "C" void kernel_launch(void* const* d_in, const int* in_sizes, int n_in,
                              void* d_out, int out_size, void* d_ws, size_t ws_size,
                              hipStream_t stream) {
    const float* x   = (const float*)d_in[0];
    const void*  ei  = d_in[1];
    const float* W1  = (const float*)d_in[2];
    const float* b1  = (const float*)d_in[3];
    const float* W2  = (const float*)d_in[4];
    const float* b2  = (const float*)d_in[5];
    const float* Wfc = (const float*)d_in[6];
    const float* bfc = (const float*)d_in[7];
    float* out = (float*)d_out;

    const int n = in_sizes[0] / 128;                 // 100000
    const int E = in_sizes[1] / 2;                   // 1600000
    const int B = (n + 127) >> 7;                    // 782 buckets
    const size_t BCAP = (size_t)B << CAPB_LOG;       // fixed-capacity region total

    size_t off = 0;
    auto alloc = [&](size_t bytes) -> void* {
        void* p = (char*)d_ws + off;
        off += (bytes + 255) & ~(size_t)255;
        return p;
    };
    int*   bucket_cursor = (int*)alloc((size_t)NBUCK_MAX * 4);
    unsigned int* packed = (unsigned int*)alloc(BCAP * 4);
    int*   csr     = (int*)  alloc(BCAP * 4);
    int*   offsets = (int*)  alloc((size_t)n * 4);
    int*   count   = (int*)  alloc((size_t)n * 4);
    float* dinv    = (float*)alloc((size_t)n * 4);
    unsigned int* hs1    = (unsigned int*)alloc((size_t)n * 64 * 2);  // bf16
    unsigned int* h1post = (unsigned int*)alloc((size_t)n * 64 * 2);  // bf16
    unsigned int* hs2    = (unsigned int*)alloc((size_t)n * 32 * 2);  // bf16
    uint4* w1f   = (uint4*)alloc(1024 * 16);
    uint4* w2f   = (uint4*)alloc(256 * 16);
    int*   flag  = (int*)  alloc(4);
    (void)ws_size;

    const int GB = (n + 63) / 64;                    // MFMA gemm blocks (1563)
    const int AG = (n + 3) / 4;
    const int PREP = 1 + (B + THREADS - 1) / THREADS;
    const int SB = (E + THREADS * SC_EPT - 1) / (THREADS * SC_EPT);   // 391 scatter blocks

    k_prep<<<PREP, THREADS, 0, stream>>>((const unsigned int*)ei, flag, bucket_cursor, B,
                                         W1, W2, w1f, w2f);
    k_scatter_gemm1<<<SB + GB, THREADS, 0, stream>>>(ei, flag, bucket_cursor, packed, E, B, SB,
                                                     x, w1f, (unsigned short*)hs1, n);
    k_fine_sort<<<B, THREADS, 0, stream>>>(packed, bucket_cursor, csr, offsets, count, dinv, n, B);
    k_agg1<<<AG, THREADS, 0, stream>>>(hs1, csr, offsets, count, dinv, b1, h1post, n);
    k_gemm2<<<GB, THREADS, 0, stream>>>((const uint4*)h1post, w2f, dinv, (unsigned short*)hs2, n);
    k_agg2_head<<<AG, THREADS, 0, stream>>>(hs2, csr, offsets, count, dinv, b2, Wfc, bfc, out, n);
}

// Round 17
// 130.225 us; speedup vs baseline: 1.0874x; 1.0134x over previous
//
#include <hip/hip_runtime.h>
#include <hip/hip_bf16.h>
#include <stdint.h>

// GCN 2-layer + linear head. bf16 node tables + MFMA GEMMs (16x16x32 bf16).
// CSR build = fixed-capacity bucket sort (4096/bucket), register-staged
// single-pass scatter grid-fused with gemm1 (no dinv prescale). agg1 folds
// dinv[src] via one per-chunk gather + UNCONDITIONAL shfl broadcast, applied
// as (0/1 mask) * shfl(dvv)  -- the shfl feeds an unconditional multiply so
// it cannot be predicated under the divergent tail condition (rounds 14/15
// failed because a ternary-guarded __shfl let the compiler execute
// ds_bpermute with EXEC-masked source lanes -> undefined values).
// fine_sort single-cursor rank order preserved (numerics-relevant).
// agg kernels are at their compulsory per-XCD L2-fill floor.

#define THREADS 256
#define NBUCK_MAX 1024
#define CAP 4096
#define CAPB_LOG 12          // 4096 entries per bucket, fixed
#define SC_EPT 16            // edges per thread in scatter (4096/block)

typedef __attribute__((ext_vector_type(8))) short short8;
typedef __attribute__((ext_vector_type(4))) float f32x4;
union frag_u { uint4 u4; short8 s8; };

__device__ __forceinline__ unsigned int pack_bf2(float a, float b) {
    unsigned int ua = __float_as_uint(a);
    unsigned int ub = __float_as_uint(b);
    ua = (ua + 0x7FFFu + ((ua >> 16) & 1u)) >> 16;
    ub = (ub + 0x7FFFu + ((ub >> 16) & 1u)) >> 16;
    return ua | (ub << 16);
}
__device__ __forceinline__ unsigned short bf16r(float a) {
    unsigned int ua = __float_as_uint(a);
    return (unsigned short)((ua + 0x7FFFu + ((ua >> 16) & 1u)) >> 16);
}
__device__ __forceinline__ float bf_lo(unsigned int u) { return __uint_as_float(u << 16); }
__device__ __forceinline__ float bf_hi(unsigned int u) { return __uint_as_float(u & 0xFFFF0000u); }

__device__ __forceinline__ int detect64(const unsigned int* w) {
    int is64 = 1;
    #pragma unroll
    for (int i = 1; i < 64; i += 2) {
        if (w[i] != 0u) { is64 = 0; break; }
    }
    return is64;
}

// block 0: dtype flag + pack W1/W2 into MFMA B-frag layout; blocks 1+: init cursors.
__global__ void k_prep(const unsigned int* ei_words, int* flag,
                       int* bucket_cursor, int B,
                       const float* __restrict__ W1, const float* __restrict__ W2,
                       uint4* __restrict__ w1f, uint4* __restrict__ w2f) {
    int b = blockIdx.x;
    int t = threadIdx.x;
    if (b == 0) {
        if (t == 0) *flag = detect64(ei_words);
        // B-frag (16x16x32): lane l, elem e -> B[k][c], k = kt*32+(l>>4)*8+e, c = ct*16+(l&15).
        for (int i = t; i < 1024; i += THREADS) {
            int l = i & 63;
            int f = i >> 6;                 // ct*4 + kt
            int ct = f >> 2, kt = f & 3;
            int c = ct * 16 + (l & 15);
            int k0 = kt * 32 + (l >> 4) * 8;
            unsigned int r0 = pack_bf2(W1[(k0 + 0) * 64 + c], W1[(k0 + 1) * 64 + c]);
            unsigned int r1 = pack_bf2(W1[(k0 + 2) * 64 + c], W1[(k0 + 3) * 64 + c]);
            unsigned int r2 = pack_bf2(W1[(k0 + 4) * 64 + c], W1[(k0 + 5) * 64 + c]);
            unsigned int r3 = pack_bf2(W1[(k0 + 6) * 64 + c], W1[(k0 + 7) * 64 + c]);
            w1f[i] = make_uint4(r0, r1, r2, r3);
        }
        {
            int l = t & 63;
            int f = t >> 6;                 // ct*2 + kt
            int ct = f >> 1, kt = f & 1;
            int c = ct * 16 + (l & 15);
            int k0 = kt * 32 + (l >> 4) * 8;
            unsigned int r0 = pack_bf2(W2[(k0 + 0) * 32 + c], W2[(k0 + 1) * 32 + c]);
            unsigned int r1 = pack_bf2(W2[(k0 + 2) * 32 + c], W2[(k0 + 3) * 32 + c]);
            unsigned int r2 = pack_bf2(W2[(k0 + 4) * 32 + c], W2[(k0 + 5) * 32 + c]);
            unsigned int r3 = pack_bf2(W2[(k0 + 6) * 32 + c], W2[(k0 + 7) * 32 + c]);
            w2f[t] = make_uint4(r0, r1, r2, r3);
        }
    } else {
        int i = (b - 1) * THREADS + t;
        if (i < B) bucket_cursor[i] = i << CAPB_LOG;
    }
}

// Grid-fused: blocks [0,SB) = register-staged scatter; blocks [SB,..) = MFMA gemm1
// (hs1 = bf16(x @ W1), NO dinv prescale). Independent workloads overlap on the CUs.
__global__ void __launch_bounds__(THREADS) k_scatter_gemm1(
        const void* ei, const int* __restrict__ flag,
        int* bucket_cursor, unsigned int* packed, int E, int B, int SB,
        const float* __restrict__ x, const uint4* __restrict__ w1f,
        unsigned short* __restrict__ hs1, int n) {
    __shared__ int h[NBUCK_MAX];
    __shared__ int base[NBUCK_MAX];
    int t = threadIdx.x;

    if ((int)blockIdx.x < SB) {
        // ---- scatter ----
        for (int i = t; i < B; i += THREADS) h[i] = 0;
        bool is64 = (*flag != 0);
        __syncthreads();
        int lo = blockIdx.x * (THREADS * SC_EPT);
        const long long* p64 = (const long long*)ei;
        const int* p32 = (const int*)ei;

        int srcv[SC_EPT], dstv[SC_EPT];
        if (is64) {
            #pragma unroll
            for (int i = 0; i < SC_EPT; ++i) {
                int e = lo + i * THREADS + t;
                int ec = (e < E) ? e : (E - 1);
                srcv[i] = (int)p64[ec];
                dstv[i] = (e < E) ? (int)p64[(size_t)E + ec] : -1;
            }
        } else {
            #pragma unroll
            for (int i = 0; i < SC_EPT; ++i) {
                int e = lo + i * THREADS + t;
                int ec = (e < E) ? e : (E - 1);
                srcv[i] = p32[ec];
                dstv[i] = (e < E) ? p32[E + ec] : -1;
            }
        }
        #pragma unroll
        for (int i = 0; i < SC_EPT; ++i)
            if (dstv[i] >= 0) atomicAdd(&h[dstv[i] >> 7], 1);
        __syncthreads();
        for (int i = t; i < B; i += THREADS) {
            int c = h[i];
            base[i] = c ? atomicAdd(&bucket_cursor[i], c) : 0;
        }
        __syncthreads();
        for (int i = t; i < B; i += THREADS) h[i] = 0;
        __syncthreads();
        #pragma unroll
        for (int i = 0; i < SC_EPT; ++i) {
            if (dstv[i] >= 0) {
                int b = dstv[i] >> 7;
                int pos = base[b] + atomicAdd(&h[b], 1);
                packed[pos] = (unsigned int)srcv[i] | ((unsigned int)(dstv[i] & 127) << 25);
            }
        }
    } else {
        // ---- MFMA gemm1: 4 waves x 16 rows; 64 cols; K=128 ----
        int gb = blockIdx.x - SB;
        int w = t >> 6, l = t & 63;
        int rowbase = gb * 64 + w * 16;

        uint4 bfr[16];
        #pragma unroll
        for (int f = 0; f < 16; ++f) bfr[f] = w1f[f * 64 + l];

        f32x4 acc[4];
        #pragma unroll
        for (int ct = 0; ct < 4; ++ct) acc[ct] = (f32x4){0.f, 0.f, 0.f, 0.f};

        int arow = rowbase + (l & 15);
        bool rv = (arow < n);
        const float* xp = x + (size_t)arow * 128 + (l >> 4) * 8;

        #pragma unroll
        for (int kt = 0; kt < 4; ++kt) {
            float4 a0 = make_float4(0.f, 0.f, 0.f, 0.f), a1 = a0;
            if (rv) {
                a0 = ((const float4*)(xp + kt * 32))[0];
                a1 = ((const float4*)(xp + kt * 32))[1];
            }
            frag_u af;
            af.u4 = make_uint4(pack_bf2(a0.x, a0.y), pack_bf2(a0.z, a0.w),
                               pack_bf2(a1.x, a1.y), pack_bf2(a1.z, a1.w));
            #pragma unroll
            for (int ct = 0; ct < 4; ++ct) {
                frag_u bfu; bfu.u4 = bfr[ct * 4 + kt];
                acc[ct] = __builtin_amdgcn_mfma_f32_16x16x32_bf16(af.s8, bfu.s8, acc[ct], 0, 0, 0);
            }
        }

        int orow0 = rowbase + (l >> 4) * 4;
        #pragma unroll
        for (int reg = 0; reg < 4; ++reg) {
            int r = orow0 + reg;
            if (r < n) {
                #pragma unroll
                for (int ct = 0; ct < 4; ++ct)
                    hs1[(size_t)r * 64 + ct * 16 + (l & 15)] = bf16r(acc[ct][reg]);
            }
        }
    }
}

// One block per bucket; size derived from final cursor. LDS hist/scan/rank over
// <=128 local nodes, staged coalesced csr write; emits offsets/count/dinv.
// Single-cursor rank order preserved (numerics-relevant, round-14 lesson).
__global__ void k_fine_sort(const unsigned int* __restrict__ packed,
                            const int* __restrict__ bucket_cursor,
                            int* __restrict__ csr, int* __restrict__ offsets,
                            int* __restrict__ countp, float* __restrict__ dinv,
                            int n, int B) {
    __shared__ unsigned int words[CAP];
    __shared__ int srcstage[CAP];
    __shared__ int cnt[128];
    __shared__ int scanv[128];
    __shared__ int cursor[128];
    int b = blockIdx.x;
    int t = threadIdx.x;
    int base = b << CAPB_LOG;
    int size = bucket_cursor[b] - base;
    if (t < 128) cnt[t] = 0;
    __syncthreads();
    for (int i0 = 0; i0 < size; i0 += THREADS) {
        int i = i0 + t;
        if (i < size) {
            unsigned int w = packed[base + i];
            words[i] = w;
            atomicAdd(&cnt[(w >> 25) & 127], 1);
        }
    }
    __syncthreads();
    if (t < 128) scanv[t] = cnt[t];
    __syncthreads();
    for (int off = 1; off < 128; off <<= 1) {
        int v = 0;
        if (t < 128 && t >= off) v = scanv[t - off];
        __syncthreads();
        if (t < 128) scanv[t] += v;
        __syncthreads();
    }
    if (t < 128) {
        int ex = scanv[t] - cnt[t];
        scanv[t] = ex;
        cursor[t] = ex;
        int node = (b << 7) + t;
        if (node < n) {
            offsets[node] = base + ex;
            countp[node] = cnt[t];
            dinv[node] = rsqrtf((float)(cnt[t] + 1));
        }
    }
    __syncthreads();
    for (int i0 = 0; i0 < size; i0 += THREADS) {
        int i = i0 + t;
        if (i < size) {
            unsigned int w = words[i];
            int d = (w >> 25) & 127;
            int rank = atomicAdd(&cursor[d], 1);
            srcstage[rank] = (int)(w & 0x1FFFFFFu);
        }
    }
    __syncthreads();
    for (int i0 = 0; i0 < size; i0 += THREADS) {
        int i = i0 + t;
        if (i < size) csr[base + i] = srcstage[i];
    }
}

// One wave per node. 64-wide CSR preload + one dinv gather per chunk; idx and
// dvv broadcast via UNCONDITIONAL shfl; tail handled by 0/1 mask * shfl(dvv).
// 16 edges/iter (4 groups x 4-deep).
__global__ void k_agg1(const unsigned int* __restrict__ hs1, const int* __restrict__ csr,
                       const int* __restrict__ offsets, const int* __restrict__ count,
                       const float* __restrict__ dinv, const float* __restrict__ b1,
                       unsigned int* __restrict__ h1post, int n) {
    int wid = threadIdx.x >> 6;
    int lane = threadIdx.x & 63;
    int node = blockIdx.x * 4 + wid;
    if (node >= n) return;
    int g  = lane >> 4;
    int f4 = lane & 15;
    int s = offsets[node];
    int c = count[node];
    float dvn = dinv[node];
    const uint2* tab = (const uint2*)hs1;

    float4 a0 = make_float4(0.f, 0.f, 0.f, 0.f);
    float4 a1 = a0, a2 = a0, a3 = a0;
    if (g == 0) {
        uint2 sv = tab[(size_t)node * 16 + f4];
        a0 = make_float4(dvn * bf_lo(sv.x), dvn * bf_hi(sv.x),
                         dvn * bf_lo(sv.y), dvn * bf_hi(sv.y));
    }

    for (int j0 = 0; j0 < c; j0 += 64) {
        int cc = min(c - j0, 64);
        int idx = csr[s + j0 + min(lane, cc - 1)];   // one coalesced 64-lane load
        float dvv = dinv[idx];                       // one 64-lane gather (L2-resident)
        for (int j = 0; j < cc; j += 16) {
            int e0 = j + g, e1 = e0 + 4, e2 = e0 + 8, e3 = e0 + 12;
            int q0 = min(e0, cc - 1), q1 = min(e1, cc - 1);
            int q2 = min(e2, cc - 1), q3 = min(e3, cc - 1);
            int s0 = __shfl(idx, q0);
            int s1 = __shfl(idx, q1);
            int s2 = __shfl(idx, q2);
            int s3 = __shfl(idx, q3);
            float d0 = __shfl(dvv, q0);              // unconditional: all lanes active
            float d1 = __shfl(dvv, q1);
            float d2 = __shfl(dvv, q2);
            float d3 = __shfl(dvv, q3);
            float m0 = ((e0 < cc) ? 1.f : 0.f) * d0; // mask applied to RESULT only
            float m1 = ((e1 < cc) ? 1.f : 0.f) * d1;
            float m2 = ((e2 < cc) ? 1.f : 0.f) * d2;
            float m3 = ((e3 < cc) ? 1.f : 0.f) * d3;
            uint2 u0 = tab[(size_t)s0 * 16 + f4];
            uint2 u1 = tab[(size_t)s1 * 16 + f4];
            uint2 u2 = tab[(size_t)s2 * 16 + f4];
            uint2 u3 = tab[(size_t)s3 * 16 + f4];
            a0.x = fmaf(m0, bf_lo(u0.x), a0.x); a0.y = fmaf(m0, bf_hi(u0.x), a0.y);
            a0.z = fmaf(m0, bf_lo(u0.y), a0.z); a0.w = fmaf(m0, bf_hi(u0.y), a0.w);
            a1.x = fmaf(m1, bf_lo(u1.x), a1.x); a1.y = fmaf(m1, bf_hi(u1.x), a1.y);
            a1.z = fmaf(m1, bf_lo(u1.y), a1.z); a1.w = fmaf(m1, bf_hi(u1.y), a1.w);
            a2.x = fmaf(m2, bf_lo(u2.x), a2.x); a2.y = fmaf(m2, bf_hi(u2.x), a2.y);
            a2.z = fmaf(m2, bf_lo(u2.y), a2.z); a2.w = fmaf(m2, bf_hi(u2.y), a2.w);
            a3.x = fmaf(m3, bf_lo(u3.x), a3.x); a3.y = fmaf(m3, bf_hi(u3.x), a3.y);
            a3.z = fmaf(m3, bf_lo(u3.y), a3.z); a3.w = fmaf(m3, bf_hi(u3.y), a3.w);
        }
    }
    a0.x += a1.x + a2.x + a3.x;
    a0.y += a1.y + a2.y + a3.y;
    a0.z += a1.z + a2.z + a3.z;
    a0.w += a1.w + a2.w + a3.w;
    a0.x += __shfl_xor(a0.x, 16); a0.y += __shfl_xor(a0.y, 16);
    a0.z += __shfl_xor(a0.z, 16); a0.w += __shfl_xor(a0.w, 16);
    a0.x += __shfl_xor(a0.x, 32); a0.y += __shfl_xor(a0.y, 32);
    a0.z += __shfl_xor(a0.z, 32); a0.w += __shfl_xor(a0.w, 32);

    if (g == 0) {
        float4 b = ((const float4*)b1)[f4];
        float ox = fmaxf(fmaf(dvn, a0.x, b.x), 0.f);
        float oy = fmaxf(fmaf(dvn, a0.y, b.y), 0.f);
        float oz = fmaxf(fmaf(dvn, a0.z, b.z), 0.f);
        float ow = fmaxf(fmaf(dvn, a0.w, b.w), 0.f);
        uint2 o;
        o.x = pack_bf2(ox, oy);
        o.y = pack_bf2(oz, ow);
        ((uint2*)h1post)[(size_t)node * 16 + f4] = o;
    }
}

// MFMA gemm2: block = 4 waves = 64 rows; 32 cols; K=64. A = h1post (bf16).
__global__ void __launch_bounds__(THREADS) k_gemm2(const uint4* __restrict__ h1,
                                                   const uint4* __restrict__ w2f,
                                                   const float* __restrict__ dinv,
                                                   unsigned short* __restrict__ hs2, int n) {
    int t = threadIdx.x;
    int w = t >> 6, l = t & 63;
    int rowbase = blockIdx.x * 64 + w * 16;

    uint4 bfr[4];
    #pragma unroll
    for (int f = 0; f < 4; ++f) bfr[f] = w2f[f * 64 + l];

    f32x4 acc[2];
    acc[0] = (f32x4){0.f, 0.f, 0.f, 0.f};
    acc[1] = (f32x4){0.f, 0.f, 0.f, 0.f};

    int arow = rowbase + (l & 15);
    bool rv = (arow < n);
    const uint4* hp = h1 + (size_t)arow * 8 + (l >> 4);

    #pragma unroll
    for (int kt = 0; kt < 2; ++kt) {
        frag_u af;
        af.u4 = rv ? hp[kt * 4] : make_uint4(0u, 0u, 0u, 0u);
        #pragma unroll
        for (int ct = 0; ct < 2; ++ct) {
            frag_u bfu; bfu.u4 = bfr[ct * 2 + kt];
            acc[ct] = __builtin_amdgcn_mfma_f32_16x16x32_bf16(af.s8, bfu.s8, acc[ct], 0, 0, 0);
        }
    }

    int orow0 = rowbase + (l >> 4) * 4;
    #pragma unroll
    for (int reg = 0; reg < 4; ++reg) {
        int r = orow0 + reg;
        if (r < n) {
            float dv = dinv[r];
            #pragma unroll
            for (int ct = 0; ct < 2; ++ct)
                hs2[(size_t)r * 32 + ct * 16 + (l & 15)] = bf16r(acc[ct][reg] * dv);
        }
    }
}

// One wave per node. 64-wide CSR preload + shfl; 16 edges/iter (8 groups x 2-deep). Fused head.
__global__ void k_agg2_head(const unsigned int* __restrict__ hs2, const int* __restrict__ csr,
                            const int* __restrict__ offsets, const int* __restrict__ count,
                            const float* __restrict__ dinv, const float* __restrict__ b2,
                            const float* __restrict__ Wfc, const float* __restrict__ bfc,
                            float* __restrict__ out, int n) {
    int wid = threadIdx.x >> 6;
    int lane = threadIdx.x & 63;
    int node = blockIdx.x * 4 + wid;
    if (node >= n) return;
    int g  = lane >> 3;
    int f4 = lane & 7;
    int s = offsets[node];
    int c = count[node];
    const uint2* tab = (const uint2*)hs2;

    float4 a0 = make_float4(0.f, 0.f, 0.f, 0.f);
    float4 a1 = a0;
    if (g == 0) {
        uint2 sv = tab[(size_t)node * 8 + f4];
        a0 = make_float4(bf_lo(sv.x), bf_hi(sv.x), bf_lo(sv.y), bf_hi(sv.y));
    }

    for (int j0 = 0; j0 < c; j0 += 64) {
        int cc = min(c - j0, 64);
        int idx = csr[s + j0 + min(lane, cc - 1)];
        for (int j = 0; j < cc; j += 16) {
            int e0 = j + g, e1 = e0 + 8;
            int s0 = __shfl(idx, min(e0, cc - 1));
            int s1 = __shfl(idx, min(e1, cc - 1));
            uint2 u0 = tab[(size_t)s0 * 8 + f4];
            uint2 u1 = tab[(size_t)s1 * 8 + f4];
            float m0 = (e0 < cc) ? 1.f : 0.f;
            float m1 = (e1 < cc) ? 1.f : 0.f;
            a0.x = fmaf(m0, bf_lo(u0.x), a0.x); a0.y = fmaf(m0, bf_hi(u0.x), a0.y);
            a0.z = fmaf(m0, bf_lo(u0.y), a0.z); a0.w = fmaf(m0, bf_hi(u0.y), a0.w);
            a1.x = fmaf(m1, bf_lo(u1.x), a1.x); a1.y = fmaf(m1, bf_hi(u1.x), a1.y);
            a1.z = fmaf(m1, bf_lo(u1.y), a1.z); a1.w = fmaf(m1, bf_hi(u1.y), a1.w);
        }
    }
    a0.x += a1.x; a0.y += a1.y; a0.z += a1.z; a0.w += a1.w;
    #pragma unroll
    for (int m = 8; m <= 32; m <<= 1) {
        a0.x += __shfl_xor(a0.x, m); a0.y += __shfl_xor(a0.y, m);
        a0.z += __shfl_xor(a0.z, m); a0.w += __shfl_xor(a0.w, m);
    }

    float dv = dinv[node];
    float4 b = ((const float4*)b2)[f4];
    float4 w = ((const float4*)Wfc)[f4];
    float hx = fmaxf(fmaf(dv, a0.x, b.x), 0.f);
    float hy = fmaxf(fmaf(dv, a0.y, b.y), 0.f);
    float hz = fmaxf(fmaf(dv, a0.z, b.z), 0.f);
    float hw = fmaxf(fmaf(dv, a0.w, b.w), 0.f);
    float p = hx * w.x + hy * w.y + hz * w.z + hw * w.w;
    p += __shfl_xor(p, 1);
    p += __shfl_xor(p, 2);
    p += __shfl_xor(p, 4);
    if (lane == 0) out[node] = p + bfc[0];
}

extern "C" void kernel_launch(void* const* d_in, const int* in_sizes, int n_in,
                              void* d_out, int out_size, void* d_ws, size_t ws_size,
                              hipStream_t stream) {
    const float* x   = (const float*)d_in[0];
    const void*  ei  = d_in[1];
    const float* W1  = (const float*)d_in[2];
    const float* b1  = (const float*)d_in[3];
    const float* W2  = (const float*)d_in[4];
    const float* b2  = (const float*)d_in[5];
    const float* Wfc = (const float*)d_in[6];
    const float* bfc = (const float*)d_in[7];
    float* out = (float*)d_out;

    const int n = in_sizes[0] / 128;                 // 100000
    const int E = in_sizes[1] / 2;                   // 1600000
    const int B = (n + 127) >> 7;                    // 782 buckets
    const size_t BCAP = (size_t)B << CAPB_LOG;       // fixed-capacity region total

    size_t off = 0;
    auto alloc = [&](size_t bytes) -> void* {
        void* p = (char*)d_ws + off;
        off += (bytes + 255) & ~(size_t)255;
        return p;
    };
    int*   bucket_cursor = (int*)alloc((size_t)NBUCK_MAX * 4);
    unsigned int* packed = (unsigned int*)alloc(BCAP * 4);
    int*   csr     = (int*)  alloc(BCAP * 4);
    int*   offsets = (int*)  alloc((size_t)n * 4);
    int*   count   = (int*)  alloc((size_t)n * 4);
    float* dinv    = (float*)alloc((size_t)n * 4);
    unsigned int* hs1    = (unsigned int*)alloc((size_t)n * 64 * 2);  // bf16
    unsigned int* h1post = (unsigned int*)alloc((size_t)n * 64 * 2);  // bf16
    unsigned int* hs2    = (unsigned int*)alloc((size_t)n * 32 * 2);  // bf16
    uint4* w1f   = (uint4*)alloc(1024 * 16);
    uint4* w2f   = (uint4*)alloc(256 * 16);
    int*   flag  = (int*)  alloc(4);
    (void)ws_size;

    const int GB = (n + 63) / 64;                    // MFMA gemm blocks (1563)
    const int AG = (n + 3) / 4;
    const int PREP = 1 + (B + THREADS - 1) / THREADS;
    const int SB = (E + THREADS * SC_EPT - 1) / (THREADS * SC_EPT);   // 391 scatter blocks

    k_prep<<<PREP, THREADS, 0, stream>>>((const unsigned int*)ei, flag, bucket_cursor, B,
                                         W1, W2, w1f, w2f);
    k_scatter_gemm1<<<SB + GB, THREADS, 0, stream>>>(ei, flag, bucket_cursor, packed, E, B, SB,
                                                     x, w1f, (unsigned short*)hs1, n);
    k_fine_sort<<<B, THREADS, 0, stream>>>(packed, bucket_cursor, csr, offsets, count, dinv, n, B);
    k_agg1<<<AG, THREADS, 0, stream>>>(hs1, csr, offsets, count, dinv, b1, h1post, n);
    k_gemm2<<<GB, THREADS, 0, stream>>>((const uint4*)h1post, w2f, dinv, (unsigned short*)hs2, n);
    k_agg2_head<<<AG, THREADS, 0, stream>>>(hs2, csr, offsets, count, dinv, b2, Wfc, bfc, out, n);
}